// Round 3
// baseline (749.100 us; speedup 1.0000x reference)
//
#include <hip/hip_runtime.h>

#define BN 16384   // B*N rows
#define NN 2048    // N
#define DD 64      // hidden
#define CC 16      // classes
#define DIAG_REPS 4   // diagnostic: run each kernel body 4x (idempotent)

typedef short bf16x8 __attribute__((ext_vector_type(8)));
typedef float f32x4 __attribute__((ext_vector_type(4)));
typedef unsigned short u16x4 __attribute__((ext_vector_type(4)));

__device__ __forceinline__ f32x4 mfma16(bf16x8 a, bf16x8 b, f32x4 c) {
  return __builtin_amdgcn_mfma_f32_16x16x32_bf16(a, b, c, 0, 0, 0);
}
__device__ __forceinline__ unsigned short f2bf(float f) {   // RNE
  unsigned u = __float_as_uint(f);
  return (unsigned short)((u + 0x7FFFu + ((u >> 16) & 1u)) >> 16);
}
__device__ __forceinline__ float bf2f(unsigned short h) {
  return __uint_as_float(((unsigned)h) << 16);
}

// ---------------- threefry-2x32 dropout mask (JAX key(42)) ----------------
__device__ __forceinline__ unsigned tf_bits(unsigned i) {
  unsigned x0 = 0u;
  unsigned x1 = i;
  const unsigned k0 = 0u, k1 = 42u, k2 = 0x1BD11BDAu ^ 0u ^ 42u;
  x0 += k0; x1 += k1;
#define TFR(r) { x0 += x1; x1 = (x1 << (r)) | (x1 >> (32 - (r))); x1 ^= x0; }
  TFR(13) TFR(15) TFR(26) TFR(6)
  x0 += k1; x1 += k2 + 1u;
  TFR(17) TFR(29) TFR(16) TFR(24)
  x0 += k2; x1 += k0 + 2u;
  TFR(13) TFR(15) TFR(26) TFR(6)
  x0 += k0; x1 += k1 + 3u;
  TFR(17) TFR(29) TFR(16) TFR(24)
  x0 += k1; x1 += k2 + 4u;
  TFR(13) TFR(15) TFR(26) TFR(6)
  x0 += k2; x1 += k0 + 5u;
#undef TFR
  return x0 ^ x1;
}

// ==================== bf16-MFMA 3-KERNEL PATH (R1 + diag reps) ============

// ---- k_deg: degrees + A->bf16 + Y1 = dis*(X@W1) (fused; one pass over A) -
__global__ __launch_bounds__(256) void k_deg(const float* __restrict__ A,
    const float* __restrict__ X, const float* __restrict__ W1,
    float* __restrict__ dis, unsigned short* __restrict__ Abf,
    unsigned short* __restrict__ Y1s, unsigned short* __restrict__ Y1sT)
{
  const int w = threadIdx.x >> 6, lane = threadIdx.x & 63;
  const size_t row = (size_t)blockIdx.x * 4 + w;
#pragma unroll 1
  for (int rep = 0; rep < DIAG_REPS; ++rep) {
    size_t z = 0; asm volatile("" : "+s"(z));    // defeat cross-rep CSE
    const float4* Arow = (const float4*)(A + z + row * NN);
    unsigned short* Brow = Abf + z + row * NN;
    float s = 0.f;
#pragma unroll
    for (int it = 0; it < 8; ++it) {
      float4 v = Arow[lane + 64 * it];
      s += (v.x + v.y) + (v.z + v.w);
      u16x4 p = { f2bf(v.x), f2bf(v.y), f2bf(v.z), f2bf(v.w) };
      *(u16x4*)(Brow + lane * 4 + it * 256) = p;
    }
#pragma unroll
    for (int m = 32; m; m >>= 1) s += __shfl_xor(s, m, 64);
    const float dv = 1.0f / sqrtf(s + 1.0f);   // A_tilda = A + I
    if (lane == 0) dis[row] = dv;
    // Y1 row (fp32 accumulate): X row is wave-uniform -> scalar loads
    const float* Xr = X + z + row * DD;
    float acc = 0.f;
#pragma unroll
    for (int k = 0; k < DD; ++k) acc += Xr[k] * W1[k * DD + lane];
    const unsigned short yv = f2bf(dv * acc);
    Y1s[row * DD + lane] = yv;
    const int b = (int)(row >> 11), kr = (int)(row & (NN - 1));
    Y1sT[((size_t)b * DD + lane) * NN + kr] = yv;   // transposed (B-operand)
  }
}

// ---- k_gemm1f: fused layer-1 + layer-2 projection ------------------------
// 16 rows x 64 cols (full hidden) per block; 4 waves K-split 4x512, LDS
// reduce; epilogue = dropout(relu(dis*(A@Y1 + diag) + b1)) kept in LDS,
// then Y2 = dis*(h@W2) computed in-block -> Y2sT bf16 + S2d fp32.
__global__ __launch_bounds__(256, 4) void k_gemm1f(const unsigned short* __restrict__ Abf,
    const unsigned short* __restrict__ Y1sT, const unsigned short* __restrict__ Y1s,
    const float* __restrict__ dis, const float* __restrict__ b1,
    const float* __restrict__ W2,
    unsigned short* __restrict__ Y2sT, float* __restrict__ S2d)
{
  __shared__ float red[4][16][68];      // wave partials, later reused for h
  __shared__ float W2l[DD * CC];        // 4 KB
  const int tid = threadIdx.x;
  *(float4*)(W2l + tid * 4) = *(const float4*)(W2 + tid * 4);   // 1024 floats
  const int Mb = blockIdx.x;                       // 0..1023 (16-row tiles)
  const int w = __builtin_amdgcn_readfirstlane((int)tid >> 6);
  const int lane = tid & 63;
  const int m15 = lane & 15, quad = lane >> 4;
  const int b = Mb >> 7;                           // 128 Mb per batch
  const int k0 = w * 512 + quad * 8;               // wave K-split
#pragma unroll 1
  for (int rep = 0; rep < DIAG_REPS; ++rep) {
    __syncthreads();   // rep>0: red[] reads done; rep0: W2l ready (early)
    size_t z = 0; asm volatile("" : "+s"(z));      // defeat cross-rep CSE
    const unsigned short* Ap  = Abf + z + ((size_t)Mb * 16 + m15) * NN + k0;
    const unsigned short* Bp0 = Y1sT + z + ((size_t)b * DD + m15) * NN + k0;
    const unsigned short* Bp1 = Bp0 + (size_t)16 * NN;
    const unsigned short* Bp2 = Bp0 + (size_t)32 * NN;
    const unsigned short* Bp3 = Bp0 + (size_t)48 * NN;
    const f32x4 zero = 0.f;
    f32x4 acc[4];
    acc[0] = zero; acc[1] = zero; acc[2] = zero; acc[3] = zero;
    bf16x8 a  = *(const bf16x8*)Ap;
    bf16x8 b0 = *(const bf16x8*)Bp0, b1v = *(const bf16x8*)Bp1;
    bf16x8 b2v = *(const bf16x8*)Bp2, b3v = *(const bf16x8*)Bp3;
#pragma unroll 1
    for (int kk = 0; kk < 16; ++kk) {
      const int off = (kk < 15) ? (kk + 1) * 32 : 0;  // wrap: harmless
      bf16x8 na  = *(const bf16x8*)(Ap + off);
      bf16x8 nb0 = *(const bf16x8*)(Bp0 + off);
      bf16x8 nb1 = *(const bf16x8*)(Bp1 + off);
      bf16x8 nb2 = *(const bf16x8*)(Bp2 + off);
      bf16x8 nb3 = *(const bf16x8*)(Bp3 + off);
      acc[0] = mfma16(a, b0,  acc[0]);
      acc[1] = mfma16(a, b1v, acc[1]);
      acc[2] = mfma16(a, b2v, acc[2]);
      acc[3] = mfma16(a, b3v, acc[3]);
      a = na; b0 = nb0; b1v = nb1; b2v = nb2; b3v = nb3;
    }
    // write wave partials to LDS (C layout: row=quad*4+r, col=ni*16+m15)
#pragma unroll
    for (int ni = 0; ni < 4; ++ni)
#pragma unroll
      for (int r = 0; r < 4; ++r)
        red[w][quad * 4 + r][ni * 16 + m15] = acc[ni][r];
    __syncthreads();
    // reduce 4 wave-partials + layer-1 epilogue; thread: 1 row x 4 cols
    const int rowl = tid >> 4, c0 = (tid & 15) * 4;
    f32x4 sum = *(const f32x4*)&red[0][rowl][c0];
    sum += *(const f32x4*)&red[1][rowl][c0];
    sum += *(const f32x4*)&red[2][rowl][c0];
    sum += *(const f32x4*)&red[3][rowl][c0];
    const int grow = Mb * 16 + rowl;
    const u16x4 y1d = *(const u16x4*)(Y1s + (size_t)grow * DD + c0);
    const float4 b1q = *(const float4*)(b1 + c0);
    const float dv = dis[grow];
    const unsigned o0 = (unsigned)grow * DD + c0;
    f32x4 hq;
#pragma unroll
    for (int j = 0; j < 4; ++j) {
      const float zv = sum[j] + bf2f(y1d[j]);
      const float bj = j == 0 ? b1q.x : j == 1 ? b1q.y : j == 2 ? b1q.z : b1q.w;
      float h = fmaxf(dv * zv + bj, 0.f);
      const unsigned bits = tf_bits(o0 + j);
      hq[j] = (bits >> 31) ? 0.f : (h + h);  // p=0.5, x2
    }
    __syncthreads();                          // all reads of red[] done
    *(f32x4*)&red[0][rowl][c0] = hq;          // h tile (16x64 fp32)
    __syncthreads();
    // Y2 = dis*(h@W2): 16x16 outputs, one per thread, K=64
    const float* hrow = &red[0][rowl][0];
    const int c2 = tid & 15;
    float s = 0.f;
#pragma unroll
    for (int k = 0; k < DD; ++k) s += hrow[k] * W2l[k * CC + c2];
    const float y2 = dv * s;
    S2d[(size_t)grow * CC + c2] = y2;                 // layer-2 diag (fp32)
    const int kr = grow & (NN - 1);
    Y2sT[((size_t)b * CC + c2) * NN + kr] = f2bf(y2); // transposed
  }
}

// ---- k_gemm2o: out = dis*(A@Y2 + diag) + b2 (fused final) ----------------
// 16 rows x 16 cols per block; 4 waves K-split 4x512, LDS reduce. grid 1024.
__global__ __launch_bounds__(256, 4) void k_gemm2o(const unsigned short* __restrict__ Abf,
    const unsigned short* __restrict__ Y2sT, const float* __restrict__ S2d,
    const float* __restrict__ dis, const float* __restrict__ b2,
    float* __restrict__ out)
{
  __shared__ float red[4][16][20];
  const int Mb = blockIdx.x;                      // 0..1023 (16-row tiles)
  const int w = __builtin_amdgcn_readfirstlane((int)threadIdx.x >> 6);
  const int lane = threadIdx.x & 63;
  const int m15 = lane & 15, quad = lane >> 4;
  const int b = Mb >> 7;                          // 128 Mb per batch
  const int k0 = w * 512 + quad * 8;
#pragma unroll 1
  for (int rep = 0; rep < DIAG_REPS; ++rep) {
    __syncthreads();   // rep>0: red[] reads from prior rep done
    size_t z = 0; asm volatile("" : "+s"(z));     // defeat cross-rep CSE
    const unsigned short* Ap = Abf + z + ((size_t)Mb * 16 + m15) * NN + k0;
    const unsigned short* Bp = Y2sT + z + ((size_t)b * CC + m15) * NN + k0;
    f32x4 acc = 0.f;
    bf16x8 a = *(const bf16x8*)Ap;
    bf16x8 bb = *(const bf16x8*)Bp;
#pragma unroll 1
    for (int kk = 0; kk < 16; ++kk) {
      const int off = (kk < 15) ? (kk + 1) * 32 : 0;
      bf16x8 na = *(const bf16x8*)(Ap + off);
      bf16x8 nbb = *(const bf16x8*)(Bp + off);
      acc = mfma16(a, bb, acc);
      a = na; bb = nbb;
    }
#pragma unroll
    for (int r = 0; r < 4; ++r)
      red[w][quad * 4 + r][m15] = acc[r];
    __syncthreads();
    const int tid = threadIdx.x;
    const int rowl = tid >> 4, c = tid & 15;         // 256 = 16x16
    const float sum = red[0][rowl][c] + red[1][rowl][c]
                    + red[2][rowl][c] + red[3][rowl][c];
    const int grow = Mb * 16 + rowl;
    out[(size_t)grow * CC + c] =
        dis[grow] * (sum + S2d[(size_t)grow * CC + c]) + b2[c];
  }
}

// ==================== FALLBACK fp32 PATH (R3, proven) ====================
#define FKS1 4
#define FKS2 16

__global__ __launch_bounds__(256) void d_deg_xw(const float* __restrict__ A,
    const float* __restrict__ X, const float* __restrict__ W1,
    float* __restrict__ dis, float* __restrict__ Y1s)
{
  const int w = threadIdx.x >> 6, lane = threadIdx.x & 63;
  const int row = __builtin_amdgcn_readfirstlane(blockIdx.x * 4 + w);
  const float4* Arow = (const float4*)(A + (size_t)row * NN);
  float s = 0.f;
#pragma unroll
  for (int it = 0; it < 8; ++it) {
    float4 v = Arow[lane + 64 * it];
    s += v.x + v.y + v.z + v.w;
  }
#pragma unroll
  for (int m = 32; m; m >>= 1) s += __shfl_xor(s, m, 64);
  const float dv = 1.0f / sqrtf(s + 1.0f);
  if (lane == 0) dis[row] = dv;
  const float* Xr = X + (size_t)row * DD;
  float acc = 0.f;
#pragma unroll
  for (int k = 0; k < DD; ++k) acc += Xr[k] * W1[k * DD + lane];
  Y1s[(size_t)row * DD + lane] = dv * acc;
}

__global__ __launch_bounds__(256) void d_gemm1(const float* __restrict__ A,
    const float* __restrict__ Y1s, float* __restrict__ Z1)
{
  const int rb = blockIdx.x >> 2, ks = blockIdx.x & (FKS1 - 1);
  const int lane = threadIdx.x & 63;
  const int c0 = __builtin_amdgcn_readfirstlane((threadIdx.x >> 6) << 4);
  const int row = rb * 64 + lane;
  const int batch = rb >> 5;
  const int KSEG = NN / FKS1;
  const float* Arow = A + (size_t)row * NN + ks * KSEG;
  const float* Yb = Y1s + (size_t)batch * NN * DD + c0;
  const int kbase = ks * KSEG;
  float acc[16];
#pragma unroll
  for (int c = 0; c < 16; ++c) acc[c] = 0.f;
  float4 a0 = *(const float4*)(Arow);
  float4 a1 = *(const float4*)(Arow + 4);
  float4 a2 = *(const float4*)(Arow + 8);
  float4 a3 = *(const float4*)(Arow + 12);
  for (int k = 0; k < KSEG; k += 16) {
    const int kn = (k + 16 < KSEG) ? (k + 16) : 0;
    float4 n0 = *(const float4*)(Arow + kn);
    float4 n1 = *(const float4*)(Arow + kn + 4);
    float4 n2 = *(const float4*)(Arow + kn + 8);
    float4 n3 = *(const float4*)(Arow + kn + 12);
    const float* y0 = Yb + (size_t)(kbase + k) * DD;
    const float av[16] = {a0.x, a0.y, a0.z, a0.w, a1.x, a1.y, a1.z, a1.w,
                          a2.x, a2.y, a2.z, a2.w, a3.x, a3.y, a3.z, a3.w};
#pragma unroll
    for (int j = 0; j < 16; ++j) {
      const float* yr = y0 + j * DD;
#pragma unroll
      for (int c = 0; c < 16; ++c) acc[c] += av[j] * yr[c];
    }
    a0 = n0; a1 = n1; a2 = n2; a3 = n3;
  }
  float* Zp = Z1 + ((size_t)ks * BN + row) * DD + c0;
#pragma unroll
  for (int c = 0; c < 16; c += 4) {
    float4 v; v.x = acc[c]; v.y = acc[c+1]; v.z = acc[c+2]; v.w = acc[c+3];
    *(float4*)(Zp + c) = v;
  }
}

__global__ __launch_bounds__(256) void d_epi1(const float* __restrict__ Z1,
    const float* __restrict__ Y1s, const float* __restrict__ dis,
    const float* __restrict__ b1, const float* __restrict__ W2,
    float* __restrict__ Y2s)
{
  __shared__ float W2l[DD * CC];
  __shared__ float hl[4][DD];
  const int tid = threadIdx.x;
  *(float4*)(W2l + tid * 4) = *(const float4*)(W2 + tid * 4);
  const int w = tid >> 6, lane = tid & 63;
  const int row = blockIdx.x * 4 + w;
  const size_t o = (size_t)row * DD + lane;
  float z = Y1s[o];
#pragma unroll
  for (int p = 0; p < FKS1; ++p) z += Z1[(size_t)p * BN * DD + o];
  const float dv = dis[row];
  float h = fmaxf(dv * z + b1[lane], 0.f);
  const unsigned bits = tf_bits((unsigned)o);
  h = (bits >> 31) ? 0.f : (h + h);
  hl[w][lane] = h;
  __syncthreads();
  const int wr = tid >> 6, l = tid & 63;
  const int c = l & 15, kq = l >> 4;
  float p = 0.f;
#pragma unroll
  for (int kk = 0; kk < 16; ++kk)
    p += hl[wr][kq * 16 + kk] * W2l[(kq * 16 + kk) * CC + c];
  p += __shfl_xor(p, 16, 64);
  p += __shfl_xor(p, 32, 64);
  if (l < 16) {
    const int rg = blockIdx.x * 4 + wr;
    Y2s[(size_t)rg * CC + c] = dis[rg] * p;
  }
}

__global__ __launch_bounds__(256) void d_gemm2(const float* __restrict__ A,
    const float* __restrict__ Y2s, float* __restrict__ Z2)
{
  const int rb = blockIdx.x >> 4, ks = blockIdx.x & (FKS2 - 1);
  const int row = rb * 256 + threadIdx.x;
  const int batch = rb >> 3;
  const int KSEG = NN / FKS2;
  const float* Arow = A + (size_t)row * NN + ks * KSEG;
  const float* Yb = Y2s + (size_t)batch * NN * CC;
  const int kbase = ks * KSEG;
  float acc[16];
#pragma unroll
  for (int c = 0; c < 16; ++c) acc[c] = 0.f;
  float4 a0 = *(const float4*)(Arow);
  float4 a1 = *(const float4*)(Arow + 4);
  for (int k = 0; k < KSEG; k += 8) {
    const int kn = (k + 8 < KSEG) ? (k + 8) : 0;
    float4 n0 = *(const float4*)(Arow + kn);
    float4 n1 = *(const float4*)(Arow + kn + 4);
    const float av[8] = {a0.x, a0.y, a0.z, a0.w, a1.x, a1.y, a1.z, a1.w};
#pragma unroll
    for (int j = 0; j < 8; ++j) {
      const float* yr = Yb + (size_t)(kbase + k + j) * CC;
#pragma unroll
      for (int c = 0; c < 16; ++c) acc[c] += av[j] * yr[c];
    }
    a0 = n0; a1 = n1;
  }
  float* Zp = Z2 + ((size_t)ks * BN + row) * CC;
#pragma unroll
  for (int c = 0; c < 16; c += 4) {
    float4 v; v.x = acc[c]; v.y = acc[c+1]; v.z = acc[c+2]; v.w = acc[c+3];
    *(float4*)(Zp + c) = v;
  }
}

__global__ __launch_bounds__(256) void d_final(const float* __restrict__ Z2,
    const float* __restrict__ Y2s, const float* __restrict__ dis,
    const float* __restrict__ b2, float* __restrict__ out)
{
  const int gid = blockIdx.x * 256 + threadIdx.x;
  const int r = gid >> 2, q = gid & 3;
  const size_t o = (size_t)r * CC + q * 4;
  float4 s = *(const float4*)(Y2s + o);
#pragma unroll
  for (int p = 0; p < FKS2; ++p) {
    const float4 zp = *(const float4*)(Z2 + (size_t)p * BN * CC + o);
    s.x += zp.x; s.y += zp.y; s.z += zp.z; s.w += zp.w;
  }
  const float dv = dis[r];
  const float4 bb = *(const float4*)(b2 + q * 4);
  float4 res;
  res.x = dv * s.x + bb.x;
  res.y = dv * s.y + bb.y;
  res.z = dv * s.z + bb.z;
  res.w = dv * s.w + bb.w;
  *(float4*)(out + o) = res;
}

extern "C" void kernel_launch(void* const* d_in, const int* in_sizes, int n_in,
                              void* d_out, int out_size, void* d_ws, size_t ws_size,
                              hipStream_t stream) {
  const float* X  = (const float*)d_in[0];
  const float* A  = (const float*)d_in[1];
  const float* W1 = (const float*)d_in[2];
  const float* b1 = (const float*)d_in[3];
  const float* W2 = (const float*)d_in[4];
  const float* b2 = (const float*)d_in[5];
  float* out = (float*)d_out;
  char* wsb = (char*)d_ws;

  // ws layout (bytes): Abf 64MB | Y1s 2MB | Y1sT 2MB | Y2sT 0.5MB |
  // S2d 1MB | dis 64KB  => 72,941,568 total
  const size_t NEED = 72941568;
  if (ws_size >= NEED) {
    unsigned short* Abf  = (unsigned short*)wsb;
    unsigned short* Y1s  = (unsigned short*)(wsb + 67108864);
    unsigned short* Y1sT = (unsigned short*)(wsb + 69206016);
    unsigned short* Y2sT = (unsigned short*)(wsb + 71303168);
    float*          S2d  = (float*)(wsb + 71827456);
    float*          dis  = (float*)(wsb + 72876032);

    k_deg   <<<BN / 4,  256, 0, stream>>>(A, X, W1, dis, Abf, Y1s, Y1sT);
    k_gemm1f<<<BN / 16, 256, 0, stream>>>(Abf, Y1sT, Y1s, dis, b1, W2, Y2sT, S2d);
    k_gemm2o<<<1024,    256, 0, stream>>>(Abf, Y2sT, S2d, dis, b2, out);
  } else {
    // fallback: proven fp32 path (R3)
    float* ws  = (float*)d_ws;
    float* dis = ws;
    float* Y1s = ws + 16384;
    float* Z1  = Y1s + (size_t)BN * DD;
    float* Z2  = Z1;
    float* Y2s = Z1 + (size_t)FKS1 * BN * DD;

    d_deg_xw<<<BN / 4,     256, 0, stream>>>(A, X, W1, dis, Y1s);
    d_gemm1 <<<256 * FKS1, 256, 0, stream>>>(A, Y1s, Z1);
    d_epi1  <<<BN / 4,     256, 0, stream>>>(Z1, Y1s, dis, b1, W2, Y2s);
    d_gemm2 <<<64 * FKS2,  256, 0, stream>>>(A, Y2s, Z2);
    d_final <<<256,        256, 0, stream>>>(Z2, Y2s, dis, b2, out);
  }
}

// Round 4
// 271.124 us; speedup vs baseline: 2.7629x; 2.7629x over previous
//
#include <hip/hip_runtime.h>

#define BN 16384   // B*N rows
#define NN 2048    // N
#define DD 64      // hidden
#define CC 16      // classes

typedef short bf16x8 __attribute__((ext_vector_type(8)));
typedef float f32x4 __attribute__((ext_vector_type(4)));
typedef unsigned short u16x4 __attribute__((ext_vector_type(4)));

__device__ __forceinline__ f32x4 mfma16(bf16x8 a, bf16x8 b, f32x4 c) {
  return __builtin_amdgcn_mfma_f32_16x16x32_bf16(a, b, c, 0, 0, 0);
}
__device__ __forceinline__ unsigned short f2bf(float f) {   // RNE
  unsigned u = __float_as_uint(f);
  return (unsigned short)((u + 0x7FFFu + ((u >> 16) & 1u)) >> 16);
}
__device__ __forceinline__ float bf2f(unsigned short h) {
  return __uint_as_float(((unsigned)h) << 16);
}

// ---------------- threefry-2x32 dropout mask (JAX key(42)) ----------------
__device__ __forceinline__ unsigned tf_bits(unsigned i) {
  unsigned x0 = 0u;
  unsigned x1 = i;
  const unsigned k0 = 0u, k1 = 42u, k2 = 0x1BD11BDAu ^ 0u ^ 42u;
  x0 += k0; x1 += k1;
#define TFR(r) { x0 += x1; x1 = (x1 << (r)) | (x1 >> (32 - (r))); x1 ^= x0; }
  TFR(13) TFR(15) TFR(26) TFR(6)
  x0 += k1; x1 += k2 + 1u;
  TFR(17) TFR(29) TFR(16) TFR(24)
  x0 += k2; x1 += k0 + 2u;
  TFR(13) TFR(15) TFR(26) TFR(6)
  x0 += k0; x1 += k1 + 3u;
  TFR(17) TFR(29) TFR(16) TFR(24)
  x0 += k1; x1 += k2 + 4u;
  TFR(13) TFR(15) TFR(26) TFR(6)
  x0 += k2; x1 += k0 + 5u;
#undef TFR
  return x0 ^ x1;
}

// ==================== bf16-MFMA 3.5-KERNEL PATH (R4) ======================

// ---- k_deg: degrees + A->bf16 + Y1 = dis*(X@W1). NO scattered stores. ----
// The R1-R3 version also wrote Y1sT here: 64 lanes x 2B stores at 4KB
// stride = same-L2-channel camping + serialized RMW drain on every wave's
// critical path (R3 diag: 102us/rep at 1.3TB/s, all pipes idle). Moved to
// k_tr (coalesced LDS transpose).
__global__ __launch_bounds__(256) void k_deg(const float* __restrict__ A,
    const float* __restrict__ X, const float* __restrict__ W1,
    float* __restrict__ dis, unsigned short* __restrict__ Abf,
    unsigned short* __restrict__ Y1s)
{
  const int w = threadIdx.x >> 6, lane = threadIdx.x & 63;
  const size_t row = (size_t)blockIdx.x * 4 + w;
  const float4* Arow = (const float4*)(A + row * NN);
  unsigned short* Brow = Abf + row * NN;
  float s = 0.f;
#pragma unroll
  for (int it = 0; it < 8; ++it) {
    float4 v = Arow[lane + 64 * it];
    s += (v.x + v.y) + (v.z + v.w);
    u16x4 p = { f2bf(v.x), f2bf(v.y), f2bf(v.z), f2bf(v.w) };
    *(u16x4*)(Brow + lane * 4 + it * 256) = p;
  }
#pragma unroll
  for (int m = 32; m; m >>= 1) s += __shfl_xor(s, m, 64);
  const float dv = 1.0f / sqrtf(s + 1.0f);   // A_tilda = A + I
  if (lane == 0) dis[row] = dv;
  // Y1 row (fp32 accumulate): X row is wave-uniform -> scalar loads
  const float* Xr = X + row * DD;
  float acc = 0.f;
#pragma unroll
  for (int k = 0; k < DD; ++k) acc += Xr[k] * W1[k * DD + lane];
  Y1s[row * DD + lane] = f2bf(dv * acc);     // coalesced (128B/wave)
}

// ---- k_tr: Y1s [16384][64] -> Y1sT [8][64][2048] via LDS 64x64 tiles -----
// Both global sides coalesced. 2MB in + 2MB out, L2-hot. grid 256.
__global__ __launch_bounds__(256) void k_tr(const unsigned short* __restrict__ Y1s,
    unsigned short* __restrict__ Y1sT)
{
  __shared__ unsigned short lds[64][80];     // pad 80 shorts (160B stride)
  const int tid = threadIdx.x;
  const int r0 = blockIdx.x * 64;            // 64-row tile, single batch
  const int b = r0 >> 11, kr0 = r0 & (NN - 1);
  {
    const int rl = tid >> 2, c0 = (tid & 3) * 16;   // 64 rows x 16 dims
    const u16x4* src = (const u16x4*)(Y1s + ((size_t)r0 + rl) * DD + c0);
    u16x4 v0 = src[0], v1 = src[1], v2 = src[2], v3 = src[3];
    *(u16x4*)&lds[rl][c0 + 0]  = v0;
    *(u16x4*)&lds[rl][c0 + 4]  = v1;
    *(u16x4*)&lds[rl][c0 + 8]  = v2;
    *(u16x4*)&lds[rl][c0 + 12] = v3;
  }
  __syncthreads();
  {
    const int dim = tid >> 2, rs = (tid & 3) * 16;  // 64 dims x 16 rows
    u16x4 o0, o1, o2, o3;
#pragma unroll
    for (int j = 0; j < 4; ++j) {
      o0[j] = lds[rs + j][dim];
      o1[j] = lds[rs + 4 + j][dim];
      o2[j] = lds[rs + 8 + j][dim];
      o3[j] = lds[rs + 12 + j][dim];
    }
    u16x4* dst = (u16x4*)(Y1sT + ((size_t)b * DD + dim) * NN + kr0 + rs);
    dst[0] = o0; dst[1] = o1; dst[2] = o2; dst[3] = o3;
  }
}

// ---- k_gemm1f: fused layer-1 + layer-2 projection ------------------------
// 16 rows x 64 cols (full hidden) per block; 4 waves K-split 4x512, LDS
// reduce; epilogue = dropout(relu(dis*(A@Y1 + diag) + b1)) kept in LDS,
// then Y2 = dis*(h@W2) computed in-block -> Y2sT bf16 + S2d fp32.
__global__ __launch_bounds__(256, 4) void k_gemm1f(const unsigned short* __restrict__ Abf,
    const unsigned short* __restrict__ Y1sT, const unsigned short* __restrict__ Y1s,
    const float* __restrict__ dis, const float* __restrict__ b1,
    const float* __restrict__ W2,
    unsigned short* __restrict__ Y2sT, float* __restrict__ S2d)
{
  __shared__ float red[4][16][68];      // wave partials, later reused for h
  __shared__ float W2l[DD * CC];        // 4 KB
  const int tid = threadIdx.x;
  *(float4*)(W2l + tid * 4) = *(const float4*)(W2 + tid * 4);   // 1024 floats
  const int Mb = blockIdx.x;                       // 0..1023 (16-row tiles)
  const int w = __builtin_amdgcn_readfirstlane((int)tid >> 6);
  const int lane = tid & 63;
  const int m15 = lane & 15, quad = lane >> 4;
  const int b = Mb >> 7;                           // 128 Mb per batch
  const int k0 = w * 512 + quad * 8;               // wave K-split
  const unsigned short* Ap  = Abf + ((size_t)Mb * 16 + m15) * NN + k0;
  const unsigned short* Bp0 = Y1sT + ((size_t)b * DD + m15) * NN + k0;
  const unsigned short* Bp1 = Bp0 + (size_t)16 * NN;
  const unsigned short* Bp2 = Bp0 + (size_t)32 * NN;
  const unsigned short* Bp3 = Bp0 + (size_t)48 * NN;
  const f32x4 zero = 0.f;
  f32x4 acc[4];
  acc[0] = zero; acc[1] = zero; acc[2] = zero; acc[3] = zero;
  bf16x8 a  = *(const bf16x8*)Ap;
  bf16x8 b0 = *(const bf16x8*)Bp0, b1v = *(const bf16x8*)Bp1;
  bf16x8 b2v = *(const bf16x8*)Bp2, b3v = *(const bf16x8*)Bp3;
#pragma unroll 1
  for (int kk = 0; kk < 16; ++kk) {
    const int off = (kk < 15) ? (kk + 1) * 32 : 0;  // wrap: harmless re-read
    bf16x8 na  = *(const bf16x8*)(Ap + off);
    bf16x8 nb0 = *(const bf16x8*)(Bp0 + off);
    bf16x8 nb1 = *(const bf16x8*)(Bp1 + off);
    bf16x8 nb2 = *(const bf16x8*)(Bp2 + off);
    bf16x8 nb3 = *(const bf16x8*)(Bp3 + off);
    acc[0] = mfma16(a, b0,  acc[0]);
    acc[1] = mfma16(a, b1v, acc[1]);
    acc[2] = mfma16(a, b2v, acc[2]);
    acc[3] = mfma16(a, b3v, acc[3]);
    a = na; b0 = nb0; b1v = nb1; b2v = nb2; b3v = nb3;
  }
  // write wave partials to LDS (C layout: row=quad*4+r, col=ni*16+m15)
#pragma unroll
  for (int ni = 0; ni < 4; ++ni)
#pragma unroll
    for (int r = 0; r < 4; ++r)
      red[w][quad * 4 + r][ni * 16 + m15] = acc[ni][r];
  __syncthreads();
  // reduce 4 wave-partials + layer-1 epilogue; thread: 1 row x 4 cols
  const int rowl = tid >> 4, c0 = (tid & 15) * 4;
  f32x4 sum = *(const f32x4*)&red[0][rowl][c0];
  sum += *(const f32x4*)&red[1][rowl][c0];
  sum += *(const f32x4*)&red[2][rowl][c0];
  sum += *(const f32x4*)&red[3][rowl][c0];
  const int grow = Mb * 16 + rowl;
  const u16x4 y1d = *(const u16x4*)(Y1s + (size_t)grow * DD + c0);
  const float4 b1q = *(const float4*)(b1 + c0);
  const float dv = dis[grow];
  const unsigned o0 = (unsigned)grow * DD + c0;
  f32x4 hq;
#pragma unroll
  for (int j = 0; j < 4; ++j) {
    const float z = sum[j] + bf2f(y1d[j]);
    const float bj = j == 0 ? b1q.x : j == 1 ? b1q.y : j == 2 ? b1q.z : b1q.w;
    float h = fmaxf(dv * z + bj, 0.f);
    const unsigned bits = tf_bits(o0 + j);
    hq[j] = (bits >> 31) ? 0.f : (h + h);  // p=0.5, x2
  }
  __syncthreads();                          // all reads of red[] done
  *(f32x4*)&red[0][rowl][c0] = hq;          // h tile (16x64 fp32) -> red[0]
  __syncthreads();
  // Y2 = dis*(h@W2): 16x16 outputs, one per thread, K=64
  const float* hrow = &red[0][rowl][0];
  const int c2 = tid & 15;
  float s = 0.f;
#pragma unroll
  for (int k = 0; k < DD; ++k) s += hrow[k] * W2l[k * CC + c2];
  const float y2 = dv * s;
  S2d[(size_t)grow * CC + c2] = y2;                 // layer-2 diag (fp32)
  const int kr = grow & (NN - 1);
  Y2sT[((size_t)b * CC + c2) * NN + kr] = f2bf(y2); // transposed (B-operand)
}

// ---- k_gemm2o: out = dis*(A@Y2 + diag) + b2 (fused final) ----------------
// 16 rows x 16 cols per block; 4 waves K-split 4x512, LDS reduce. grid 1024.
__global__ __launch_bounds__(256, 4) void k_gemm2o(const unsigned short* __restrict__ Abf,
    const unsigned short* __restrict__ Y2sT, const float* __restrict__ S2d,
    const float* __restrict__ dis, const float* __restrict__ b2,
    float* __restrict__ out)
{
  __shared__ float red[4][16][20];
  const int Mb = blockIdx.x;                      // 0..1023 (16-row tiles)
  const int w = __builtin_amdgcn_readfirstlane((int)threadIdx.x >> 6);
  const int lane = threadIdx.x & 63;
  const int m15 = lane & 15, quad = lane >> 4;
  const int b = Mb >> 7;                          // 128 Mb per batch
  const int k0 = w * 512 + quad * 8;
  const unsigned short* Ap = Abf + ((size_t)Mb * 16 + m15) * NN + k0;
  const unsigned short* Bp = Y2sT + ((size_t)b * CC + m15) * NN + k0;
  f32x4 acc = 0.f;
  bf16x8 a = *(const bf16x8*)Ap;
  bf16x8 bb = *(const bf16x8*)Bp;
#pragma unroll 1
  for (int kk = 0; kk < 16; ++kk) {
    const int off = (kk < 15) ? (kk + 1) * 32 : 0;
    bf16x8 na = *(const bf16x8*)(Ap + off);
    bf16x8 nbb = *(const bf16x8*)(Bp + off);
    acc = mfma16(a, bb, acc);
    a = na; bb = nbb;
  }
#pragma unroll
  for (int r = 0; r < 4; ++r)
    red[w][quad * 4 + r][m15] = acc[r];
  __syncthreads();
  const int tid = threadIdx.x;
  const int rowl = tid >> 4, c = tid & 15;         // 256 = 16x16
  const float sum = red[0][rowl][c] + red[1][rowl][c]
                  + red[2][rowl][c] + red[3][rowl][c];
  const int grow = Mb * 16 + rowl;
  out[(size_t)grow * CC + c] =
      dis[grow] * (sum + S2d[(size_t)grow * CC + c]) + b2[c];
}

// ==================== FALLBACK fp32 PATH (R3, proven) ====================
#define FKS1 4
#define FKS2 16

__global__ __launch_bounds__(256) void d_deg_xw(const float* __restrict__ A,
    const float* __restrict__ X, const float* __restrict__ W1,
    float* __restrict__ dis, float* __restrict__ Y1s)
{
  const int w = threadIdx.x >> 6, lane = threadIdx.x & 63;
  const int row = __builtin_amdgcn_readfirstlane(blockIdx.x * 4 + w);
  const float4* Arow = (const float4*)(A + (size_t)row * NN);
  float s = 0.f;
#pragma unroll
  for (int it = 0; it < 8; ++it) {
    float4 v = Arow[lane + 64 * it];
    s += v.x + v.y + v.z + v.w;
  }
#pragma unroll
  for (int m = 32; m; m >>= 1) s += __shfl_xor(s, m, 64);
  const float dv = 1.0f / sqrtf(s + 1.0f);
  if (lane == 0) dis[row] = dv;
  const float* Xr = X + (size_t)row * DD;
  float acc = 0.f;
#pragma unroll
  for (int k = 0; k < DD; ++k) acc += Xr[k] * W1[k * DD + lane];
  Y1s[(size_t)row * DD + lane] = dv * acc;
}

__global__ __launch_bounds__(256) void d_gemm1(const float* __restrict__ A,
    const float* __restrict__ Y1s, float* __restrict__ Z1)
{
  const int rb = blockIdx.x >> 2, ks = blockIdx.x & (FKS1 - 1);
  const int lane = threadIdx.x & 63;
  const int c0 = __builtin_amdgcn_readfirstlane((threadIdx.x >> 6) << 4);
  const int row = rb * 64 + lane;
  const int batch = rb >> 5;
  const int KSEG = NN / FKS1;
  const float* Arow = A + (size_t)row * NN + ks * KSEG;
  const float* Yb = Y1s + (size_t)batch * NN * DD + c0;
  const int kbase = ks * KSEG;
  float acc[16];
#pragma unroll
  for (int c = 0; c < 16; ++c) acc[c] = 0.f;
  float4 a0 = *(const float4*)(Arow);
  float4 a1 = *(const float4*)(Arow + 4);
  float4 a2 = *(const float4*)(Arow + 8);
  float4 a3 = *(const float4*)(Arow + 12);
  for (int k = 0; k < KSEG; k += 16) {
    const int kn = (k + 16 < KSEG) ? (k + 16) : 0;
    float4 n0 = *(const float4*)(Arow + kn);
    float4 n1 = *(const float4*)(Arow + kn + 4);
    float4 n2 = *(const float4*)(Arow + kn + 8);
    float4 n3 = *(const float4*)(Arow + kn + 12);
    const float* y0 = Yb + (size_t)(kbase + k) * DD;
    const float av[16] = {a0.x, a0.y, a0.z, a0.w, a1.x, a1.y, a1.z, a1.w,
                          a2.x, a2.y, a2.z, a2.w, a3.x, a3.y, a3.z, a3.w};
#pragma unroll
    for (int j = 0; j < 16; ++j) {
      const float* yr = y0 + j * DD;
#pragma unroll
      for (int c = 0; c < 16; ++c) acc[c] += av[j] * yr[c];
    }
    a0 = n0; a1 = n1; a2 = n2; a3 = n3;
  }
  float* Zp = Z1 + ((size_t)ks * BN + row) * DD + c0;
#pragma unroll
  for (int c = 0; c < 16; c += 4) {
    float4 v; v.x = acc[c]; v.y = acc[c+1]; v.z = acc[c+2]; v.w = acc[c+3];
    *(float4*)(Zp + c) = v;
  }
}

__global__ __launch_bounds__(256) void d_epi1(const float* __restrict__ Z1,
    const float* __restrict__ Y1s, const float* __restrict__ dis,
    const float* __restrict__ b1, const float* __restrict__ W2,
    float* __restrict__ Y2s)
{
  __shared__ float W2l[DD * CC];
  __shared__ float hl[4][DD];
  const int tid = threadIdx.x;
  *(float4*)(W2l + tid * 4) = *(const float4*)(W2 + tid * 4);
  const int w = tid >> 6, lane = tid & 63;
  const int row = blockIdx.x * 4 + w;
  const size_t o = (size_t)row * DD + lane;
  float z = Y1s[o];
#pragma unroll
  for (int p = 0; p < FKS1; ++p) z += Z1[(size_t)p * BN * DD + o];
  const float dv = dis[row];
  float h = fmaxf(dv * z + b1[lane], 0.f);
  const unsigned bits = tf_bits((unsigned)o);
  h = (bits >> 31) ? 0.f : (h + h);
  hl[w][lane] = h;
  __syncthreads();
  const int wr = tid >> 6, l = tid & 63;
  const int c = l & 15, kq = l >> 4;
  float p = 0.f;
#pragma unroll
  for (int kk = 0; kk < 16; ++kk)
    p += hl[wr][kq * 16 + kk] * W2l[(kq * 16 + kk) * CC + c];
  p += __shfl_xor(p, 16, 64);
  p += __shfl_xor(p, 32, 64);
  if (l < 16) {
    const int rg = blockIdx.x * 4 + wr;
    Y2s[(size_t)rg * CC + c] = dis[rg] * p;
  }
}

__global__ __launch_bounds__(256) void d_gemm2(const float* __restrict__ A,
    const float* __restrict__ Y2s, float* __restrict__ Z2)
{
  const int rb = blockIdx.x >> 4, ks = blockIdx.x & (FKS2 - 1);
  const int row = rb * 256 + threadIdx.x;
  const int batch = rb >> 3;
  const int KSEG = NN / FKS2;
  const float* Arow = A + (size_t)row * NN + ks * KSEG;
  const float* Yb = Y2s + (size_t)batch * NN * CC;
  const int kbase = ks * KSEG;
  float acc[16];
#pragma unroll
  for (int c = 0; c < 16; ++c) acc[c] = 0.f;
  float4 a0 = *(const float4*)(Arow);
  float4 a1 = *(const float4*)(Arow + 4);
  for (int k = 0; k < KSEG; k += 8) {
    const int kn = (k + 8 < KSEG) ? (k + 8) : 0;
    float4 n0 = *(const float4*)(Arow + kn);
    float4 n1 = *(const float4*)(Arow + kn + 4);
    const float av[8] = {a0.x, a0.y, a0.z, a0.w, a1.x, a1.y, a1.z, a1.w};
#pragma unroll
    for (int j = 0; j < 8; ++j) {
      const float* yr = Yb + (size_t)(kbase + k + j) * CC;
#pragma unroll
      for (int c = 0; c < 16; ++c) acc[c] += av[j] * yr[c];
    }
    a0 = n0; a1 = n1;
  }
  float* Zp = Z2 + ((size_t)ks * BN + row) * CC;
#pragma unroll
  for (int c = 0; c < 16; c += 4) {
    float4 v; v.x = acc[c]; v.y = acc[c+1]; v.z = acc[c+2]; v.w = acc[c+3];
    *(float4*)(Zp + c) = v;
  }
}

__global__ __launch_bounds__(256) void d_final(const float* __restrict__ Z2,
    const float* __restrict__ Y2s, const float* __restrict__ dis,
    const float* __restrict__ b2, float* __restrict__ out)
{
  const int gid = blockIdx.x * 256 + threadIdx.x;
  const int r = gid >> 2, q = gid & 3;
  const size_t o = (size_t)r * CC + q * 4;
  float4 s = *(const float4*)(Y2s + o);
#pragma unroll
  for (int p = 0; p < FKS2; ++p) {
    const float4 zp = *(const float4*)(Z2 + (size_t)p * BN * CC + o);
    s.x += zp.x; s.y += zp.y; s.z += zp.z; s.w += zp.w;
  }
  const float dv = dis[r];
  const float4 bb = *(const float4*)(b2 + q * 4);
  float4 res;
  res.x = dv * s.x + bb.x;
  res.y = dv * s.y + bb.y;
  res.z = dv * s.z + bb.z;
  res.w = dv * s.w + bb.w;
  *(float4*)(out + o) = res;
}

extern "C" void kernel_launch(void* const* d_in, const int* in_sizes, int n_in,
                              void* d_out, int out_size, void* d_ws, size_t ws_size,
                              hipStream_t stream) {
  const float* X  = (const float*)d_in[0];
  const float* A  = (const float*)d_in[1];
  const float* W1 = (const float*)d_in[2];
  const float* b1 = (const float*)d_in[3];
  const float* W2 = (const float*)d_in[4];
  const float* b2 = (const float*)d_in[5];
  float* out = (float*)d_out;
  char* wsb = (char*)d_ws;

  // ws layout (bytes): Abf 64MB | Y1s 2MB | Y1sT 2MB | Y2sT 0.5MB |
  // S2d 1MB | dis 64KB  => 72,941,568 total
  const size_t NEED = 72941568;
  if (ws_size >= NEED) {
    unsigned short* Abf  = (unsigned short*)wsb;
    unsigned short* Y1s  = (unsigned short*)(wsb + 67108864);
    unsigned short* Y1sT = (unsigned short*)(wsb + 69206016);
    unsigned short* Y2sT = (unsigned short*)(wsb + 71303168);
    float*          S2d  = (float*)(wsb + 71827456);
    float*          dis  = (float*)(wsb + 72876032);

    k_deg   <<<BN / 4,  256, 0, stream>>>(A, X, W1, dis, Abf, Y1s);
    k_tr    <<<BN / 64, 256, 0, stream>>>(Y1s, Y1sT);
    k_gemm1f<<<BN / 16, 256, 0, stream>>>(Abf, Y1sT, Y1s, dis, b1, W2, Y2sT, S2d);
    k_gemm2o<<<1024,    256, 0, stream>>>(Abf, Y2sT, S2d, dis, b2, out);
  } else {
    // fallback: proven fp32 path (R3)
    float* ws  = (float*)d_ws;
    float* dis = ws;
    float* Y1s = ws + 16384;
    float* Z1  = Y1s + (size_t)BN * DD;
    float* Z2  = Z1;
    float* Y2s = Z1 + (size_t)FKS1 * BN * DD;

    d_deg_xw<<<BN / 4,     256, 0, stream>>>(A, X, W1, dis, Y1s);
    d_gemm1 <<<256 * FKS1, 256, 0, stream>>>(A, Y1s, Z1);
    d_epi1  <<<BN / 4,     256, 0, stream>>>(Z1, Y1s, dis, b1, W2, Y2s);
    d_gemm2 <<<64 * FKS2,  256, 0, stream>>>(A, Y2s, Z2);
    d_final <<<256,        256, 0, stream>>>(Z2, Y2s, dis, b2, out);
  }
}

// Round 5
// 269.057 us; speedup vs baseline: 2.7842x; 1.0077x over previous
//
#include <hip/hip_runtime.h>

#define BN 16384   // B*N rows
#define NN 2048    // N
#define DD 64      // hidden
#define CC 16      // classes

typedef short bf16x8 __attribute__((ext_vector_type(8)));
typedef float f32x4 __attribute__((ext_vector_type(4)));
typedef unsigned short u16x4 __attribute__((ext_vector_type(4)));

__device__ __forceinline__ f32x4 mfma16(bf16x8 a, bf16x8 b, f32x4 c) {
  return __builtin_amdgcn_mfma_f32_16x16x32_bf16(a, b, c, 0, 0, 0);
}
__device__ __forceinline__ unsigned short f2bf(float f) {   // RNE
  unsigned u = __float_as_uint(f);
  return (unsigned short)((u + 0x7FFFu + ((u >> 16) & 1u)) >> 16);
}
__device__ __forceinline__ float bf2f(unsigned short h) {
  return __uint_as_float(((unsigned)h) << 16);
}

// ---------------- threefry-2x32 dropout mask (JAX key(42)) ----------------
__device__ __forceinline__ unsigned tf_bits(unsigned i) {
  unsigned x0 = 0u;
  unsigned x1 = i;
  const unsigned k0 = 0u, k1 = 42u, k2 = 0x1BD11BDAu ^ 0u ^ 42u;
  x0 += k0; x1 += k1;
#define TFR(r) { x0 += x1; x1 = (x1 << (r)) | (x1 >> (32 - (r))); x1 ^= x0; }
  TFR(13) TFR(15) TFR(26) TFR(6)
  x0 += k1; x1 += k2 + 1u;
  TFR(17) TFR(29) TFR(16) TFR(24)
  x0 += k2; x1 += k0 + 2u;
  TFR(13) TFR(15) TFR(26) TFR(6)
  x0 += k0; x1 += k1 + 3u;
  TFR(17) TFR(29) TFR(16) TFR(24)
  x0 += k1; x1 += k2 + 4u;
  TFR(13) TFR(15) TFR(26) TFR(6)
  x0 += k2; x1 += k0 + 5u;
#undef TFR
  return x0 ^ x1;
}

// ==================== bf16-MFMA 3.5-KERNEL PATH (R5) ======================

// ---- k_deg: degrees + A->bf16 + Y1 = dis*(X@W1). (R4-identical) ----------
__global__ __launch_bounds__(256) void k_deg(const float* __restrict__ A,
    const float* __restrict__ X, const float* __restrict__ W1,
    float* __restrict__ dis, unsigned short* __restrict__ Abf,
    unsigned short* __restrict__ Y1s)
{
  const int w = threadIdx.x >> 6, lane = threadIdx.x & 63;
  const size_t row = (size_t)blockIdx.x * 4 + w;
  const float4* Arow = (const float4*)(A + row * NN);
  unsigned short* Brow = Abf + row * NN;
  float s = 0.f;
#pragma unroll
  for (int it = 0; it < 8; ++it) {
    float4 v = Arow[lane + 64 * it];
    s += (v.x + v.y) + (v.z + v.w);
    u16x4 p = { f2bf(v.x), f2bf(v.y), f2bf(v.z), f2bf(v.w) };
    *(u16x4*)(Brow + lane * 4 + it * 256) = p;
  }
#pragma unroll
  for (int m = 32; m; m >>= 1) s += __shfl_xor(s, m, 64);
  const float dv = 1.0f / sqrtf(s + 1.0f);   // A_tilda = A + I
  if (lane == 0) dis[row] = dv;
  // Y1 row (fp32 accumulate): X row is wave-uniform -> scalar loads
  const float* Xr = X + row * DD;
  float acc = 0.f;
#pragma unroll
  for (int k = 0; k < DD; ++k) acc += Xr[k] * W1[k * DD + lane];
  Y1s[row * DD + lane] = f2bf(dv * acc);     // coalesced (128B/wave)
}

// ---- k_tr: Y1s [16384][64] -> Y1sT [8][64][2048] via LDS 64x64 tiles -----
__global__ __launch_bounds__(256) void k_tr(const unsigned short* __restrict__ Y1s,
    unsigned short* __restrict__ Y1sT)
{
  __shared__ unsigned short lds[64][80];     // pad 80 shorts (160B stride)
  const int tid = threadIdx.x;
  const int r0 = blockIdx.x * 64;            // 64-row tile, single batch
  const int b = r0 >> 11, kr0 = r0 & (NN - 1);
  {
    const int rl = tid >> 2, c0 = (tid & 3) * 16;   // 64 rows x 16 dims
    const u16x4* src = (const u16x4*)(Y1s + ((size_t)r0 + rl) * DD + c0);
    u16x4 v0 = src[0], v1 = src[1], v2 = src[2], v3 = src[3];
    *(u16x4*)&lds[rl][c0 + 0]  = v0;
    *(u16x4*)&lds[rl][c0 + 4]  = v1;
    *(u16x4*)&lds[rl][c0 + 8]  = v2;
    *(u16x4*)&lds[rl][c0 + 12] = v3;
  }
  __syncthreads();
  {
    const int dim = tid >> 2, rs = (tid & 3) * 16;  // 64 dims x 16 rows
    u16x4 o0, o1, o2, o3;
#pragma unroll
    for (int j = 0; j < 4; ++j) {
      o0[j] = lds[rs + j][dim];
      o1[j] = lds[rs + 4 + j][dim];
      o2[j] = lds[rs + 8 + j][dim];
      o3[j] = lds[rs + 12 + j][dim];
    }
    u16x4* dst = (u16x4*)(Y1sT + ((size_t)b * DD + dim) * NN + kr0 + rs);
    dst[0] = o0; dst[1] = o1; dst[2] = o2; dst[3] = o3;
  }
}

// ---- k_gemm1f: fused layer-1 + layer-2 projection ------------------------
// 16 rows x 64 cols per block; 4 waves K-split 4x512, LDS reduce; full
// layer-1 epilogue + h@W2 in-block. R5: depth-4 prefetch banks in kk-loop
// (was depth-1: ~30cyc cover vs ~500cyc mem latency -> latency-bound at
// ~15% util per R2/R3 profiles). Same kk order -> bit-identical numerics.
__global__ __launch_bounds__(256, 4) void k_gemm1f(const unsigned short* __restrict__ Abf,
    const unsigned short* __restrict__ Y1sT, const unsigned short* __restrict__ Y1s,
    const float* __restrict__ dis, const float* __restrict__ b1,
    const float* __restrict__ W2,
    unsigned short* __restrict__ Y2sT, float* __restrict__ S2d)
{
  __shared__ float red[4][16][68];      // wave partials, later reused for h
  __shared__ float W2l[DD * CC];        // 4 KB
  const int tid = threadIdx.x;
  *(float4*)(W2l + tid * 4) = *(const float4*)(W2 + tid * 4);   // 1024 floats
  const int Mb = blockIdx.x;                       // 0..1023 (16-row tiles)
  const int w = __builtin_amdgcn_readfirstlane((int)tid >> 6);
  const int lane = tid & 63;
  const int m15 = lane & 15, quad = lane >> 4;
  const int b = Mb >> 7;                           // 128 Mb per batch
  const int k0 = w * 512 + quad * 8;               // wave K-split
  const unsigned short* Ap  = Abf + ((size_t)Mb * 16 + m15) * NN + k0;
  const unsigned short* Bp0 = Y1sT + ((size_t)b * DD + m15) * NN + k0;
  const unsigned short* Bp1 = Bp0 + (size_t)16 * NN;
  const unsigned short* Bp2 = Bp0 + (size_t)32 * NN;
  const unsigned short* Bp3 = Bp0 + (size_t)48 * NN;
  const f32x4 zero = 0.f;
  f32x4 acc[4];
  acc[0] = zero; acc[1] = zero; acc[2] = zero; acc[3] = zero;
#define G1_LOAD(OFF, Av, B0v, B1v, B2v, B3v) \
    Av  = *(const bf16x8*)(Ap  + (OFF)); \
    B0v = *(const bf16x8*)(Bp0 + (OFF)); \
    B1v = *(const bf16x8*)(Bp1 + (OFF)); \
    B2v = *(const bf16x8*)(Bp2 + (OFF)); \
    B3v = *(const bf16x8*)(Bp3 + (OFF));
#define G1_MFMA(Av, B0v, B1v, B2v, B3v) \
    acc[0] = mfma16(Av, B0v, acc[0]); \
    acc[1] = mfma16(Av, B1v, acc[1]); \
    acc[2] = mfma16(Av, B2v, acc[2]); \
    acc[3] = mfma16(Av, B3v, acc[3]);
  bf16x8 a0, b00, b10, b20, b30;
  bf16x8 a1, b01, b11, b21, b31;
  bf16x8 a2, b02, b12, b22, b32;
  bf16x8 a3, b03, b13, b23, b33;
  G1_LOAD(0,  a0, b00, b10, b20, b30)
  G1_LOAD(32, a1, b01, b11, b21, b31)
  G1_LOAD(64, a2, b02, b12, b22, b32)
  G1_LOAD(96, a3, b03, b13, b23, b33)
#pragma unroll 1
  for (int kk4 = 0; kk4 < 4; ++kk4) {
    const int base = kk4 * 4;
    const int o0 = (base + 4 < 16) ? (base + 4) * 32 : 0;  // wrap: harmless
    const int o1 = (base + 5 < 16) ? (base + 5) * 32 : 0;  // (never consumed)
    const int o2 = (base + 6 < 16) ? (base + 6) * 32 : 0;
    const int o3 = (base + 7 < 16) ? (base + 7) * 32 : 0;
    G1_MFMA(a0, b00, b10, b20, b30)
    G1_LOAD(o0, a0, b00, b10, b20, b30)
    G1_MFMA(a1, b01, b11, b21, b31)
    G1_LOAD(o1, a1, b01, b11, b21, b31)
    G1_MFMA(a2, b02, b12, b22, b32)
    G1_LOAD(o2, a2, b02, b12, b22, b32)
    G1_MFMA(a3, b03, b13, b23, b33)
    G1_LOAD(o3, a3, b03, b13, b23, b33)
  }
#undef G1_LOAD
#undef G1_MFMA
  // write wave partials to LDS (C layout: row=quad*4+r, col=ni*16+m15)
#pragma unroll
  for (int ni = 0; ni < 4; ++ni)
#pragma unroll
    for (int r = 0; r < 4; ++r)
      red[w][quad * 4 + r][ni * 16 + m15] = acc[ni][r];
  __syncthreads();
  // reduce 4 wave-partials + layer-1 epilogue; thread: 1 row x 4 cols
  const int rowl = tid >> 4, c0 = (tid & 15) * 4;
  f32x4 sum = *(const f32x4*)&red[0][rowl][c0];
  sum += *(const f32x4*)&red[1][rowl][c0];
  sum += *(const f32x4*)&red[2][rowl][c0];
  sum += *(const f32x4*)&red[3][rowl][c0];
  const int grow = Mb * 16 + rowl;
  const u16x4 y1d = *(const u16x4*)(Y1s + (size_t)grow * DD + c0);
  const float4 b1q = *(const float4*)(b1 + c0);
  const float dv = dis[grow];
  const unsigned o0i = (unsigned)grow * DD + c0;
  f32x4 hq;
#pragma unroll
  for (int j = 0; j < 4; ++j) {
    const float z = sum[j] + bf2f(y1d[j]);
    const float bj = j == 0 ? b1q.x : j == 1 ? b1q.y : j == 2 ? b1q.z : b1q.w;
    float h = fmaxf(dv * z + bj, 0.f);
    const unsigned bits = tf_bits(o0i + j);
    hq[j] = (bits >> 31) ? 0.f : (h + h);  // p=0.5, x2
  }
  __syncthreads();                          // all reads of red[] done
  *(f32x4*)&red[0][rowl][c0] = hq;          // h tile (16x64 fp32) -> red[0]
  __syncthreads();
  // Y2 = dis*(h@W2): 16x16 outputs, one per thread, K=64
  const float* hrow = &red[0][rowl][0];
  const int c2 = tid & 15;
  float s = 0.f;
#pragma unroll
  for (int k = 0; k < DD; ++k) s += hrow[k] * W2l[k * CC + c2];
  const float y2 = dv * s;
  S2d[(size_t)grow * CC + c2] = y2;                 // layer-2 diag (fp32)
  const int kr = grow & (NN - 1);
  Y2sT[((size_t)b * CC + c2) * NN + kr] = f2bf(y2); // transposed (B-operand)
}

// ---- k_gemm2o: out = dis*(A@Y2 + diag) + b2 (fused final) ----------------
// 16 rows x 16 cols per block; 4 waves K-split 4x512, LDS reduce.
// R5: depth-4 prefetch banks (same rationale as k_gemm1f). grid 1024.
__global__ __launch_bounds__(256, 4) void k_gemm2o(const unsigned short* __restrict__ Abf,
    const unsigned short* __restrict__ Y2sT, const float* __restrict__ S2d,
    const float* __restrict__ dis, const float* __restrict__ b2,
    float* __restrict__ out)
{
  __shared__ float red[4][16][20];
  const int Mb = blockIdx.x;                      // 0..1023 (16-row tiles)
  const int w = __builtin_amdgcn_readfirstlane((int)threadIdx.x >> 6);
  const int lane = threadIdx.x & 63;
  const int m15 = lane & 15, quad = lane >> 4;
  const int b = Mb >> 7;                          // 128 Mb per batch
  const int k0 = w * 512 + quad * 8;
  const unsigned short* Ap = Abf + ((size_t)Mb * 16 + m15) * NN + k0;
  const unsigned short* Bp = Y2sT + ((size_t)b * CC + m15) * NN + k0;
  f32x4 acc = 0.f;
#define G2_LOAD(OFF, Av, Bv) \
    Av = *(const bf16x8*)(Ap + (OFF)); \
    Bv = *(const bf16x8*)(Bp + (OFF));
  bf16x8 a0, bb0, a1, bb1, a2, bb2, a3, bb3;
  G2_LOAD(0,  a0, bb0)
  G2_LOAD(32, a1, bb1)
  G2_LOAD(64, a2, bb2)
  G2_LOAD(96, a3, bb3)
#pragma unroll 1
  for (int kk4 = 0; kk4 < 4; ++kk4) {
    const int base = kk4 * 4;
    const int o0 = (base + 4 < 16) ? (base + 4) * 32 : 0;  // wrap: harmless
    const int o1 = (base + 5 < 16) ? (base + 5) * 32 : 0;
    const int o2 = (base + 6 < 16) ? (base + 6) * 32 : 0;
    const int o3 = (base + 7 < 16) ? (base + 7) * 32 : 0;
    acc = mfma16(a0, bb0, acc);  G2_LOAD(o0, a0, bb0)
    acc = mfma16(a1, bb1, acc);  G2_LOAD(o1, a1, bb1)
    acc = mfma16(a2, bb2, acc);  G2_LOAD(o2, a2, bb2)
    acc = mfma16(a3, bb3, acc);  G2_LOAD(o3, a3, bb3)
  }
#undef G2_LOAD
#pragma unroll
  for (int r = 0; r < 4; ++r)
    red[w][quad * 4 + r][m15] = acc[r];
  __syncthreads();
  const int tid = threadIdx.x;
  const int rowl = tid >> 4, c = tid & 15;         // 256 = 16x16
  const float sum = red[0][rowl][c] + red[1][rowl][c]
                  + red[2][rowl][c] + red[3][rowl][c];
  const int grow = Mb * 16 + rowl;
  out[(size_t)grow * CC + c] =
      dis[grow] * (sum + S2d[(size_t)grow * CC + c]) + b2[c];
}

// ==================== FALLBACK fp32 PATH (R3, proven) ====================
#define FKS1 4
#define FKS2 16

__global__ __launch_bounds__(256) void d_deg_xw(const float* __restrict__ A,
    const float* __restrict__ X, const float* __restrict__ W1,
    float* __restrict__ dis, float* __restrict__ Y1s)
{
  const int w = threadIdx.x >> 6, lane = threadIdx.x & 63;
  const int row = __builtin_amdgcn_readfirstlane(blockIdx.x * 4 + w);
  const float4* Arow = (const float4*)(A + (size_t)row * NN);
  float s = 0.f;
#pragma unroll
  for (int it = 0; it < 8; ++it) {
    float4 v = Arow[lane + 64 * it];
    s += v.x + v.y + v.z + v.w;
  }
#pragma unroll
  for (int m = 32; m; m >>= 1) s += __shfl_xor(s, m, 64);
  const float dv = 1.0f / sqrtf(s + 1.0f);
  if (lane == 0) dis[row] = dv;
  const float* Xr = X + (size_t)row * DD;
  float acc = 0.f;
#pragma unroll
  for (int k = 0; k < DD; ++k) acc += Xr[k] * W1[k * DD + lane];
  Y1s[(size_t)row * DD + lane] = dv * acc;
}

__global__ __launch_bounds__(256) void d_gemm1(const float* __restrict__ A,
    const float* __restrict__ Y1s, float* __restrict__ Z1)
{
  const int rb = blockIdx.x >> 2, ks = blockIdx.x & (FKS1 - 1);
  const int lane = threadIdx.x & 63;
  const int c0 = __builtin_amdgcn_readfirstlane((threadIdx.x >> 6) << 4);
  const int row = rb * 64 + lane;
  const int batch = rb >> 5;
  const int KSEG = NN / FKS1;
  const float* Arow = A + (size_t)row * NN + ks * KSEG;
  const float* Yb = Y1s + (size_t)batch * NN * DD + c0;
  const int kbase = ks * KSEG;
  float acc[16];
#pragma unroll
  for (int c = 0; c < 16; ++c) acc[c] = 0.f;
  float4 a0 = *(const float4*)(Arow);
  float4 a1 = *(const float4*)(Arow + 4);
  float4 a2 = *(const float4*)(Arow + 8);
  float4 a3 = *(const float4*)(Arow + 12);
  for (int k = 0; k < KSEG; k += 16) {
    const int kn = (k + 16 < KSEG) ? (k + 16) : 0;
    float4 n0 = *(const float4*)(Arow + kn);
    float4 n1 = *(const float4*)(Arow + kn + 4);
    float4 n2 = *(const float4*)(Arow + kn + 8);
    float4 n3 = *(const float4*)(Arow + kn + 12);
    const float* y0 = Yb + (size_t)(kbase + k) * DD;
    const float av[16] = {a0.x, a0.y, a0.z, a0.w, a1.x, a1.y, a1.z, a1.w,
                          a2.x, a2.y, a2.z, a2.w, a3.x, a3.y, a3.z, a3.w};
#pragma unroll
    for (int j = 0; j < 16; ++j) {
      const float* yr = y0 + j * DD;
#pragma unroll
      for (int c = 0; c < 16; ++c) acc[c] += av[j] * yr[c];
    }
    a0 = n0; a1 = n1; a2 = n2; a3 = n3;
  }
  float* Zp = Z1 + ((size_t)ks * BN + row) * DD + c0;
#pragma unroll
  for (int c = 0; c < 16; c += 4) {
    float4 v; v.x = acc[c]; v.y = acc[c+1]; v.z = acc[c+2]; v.w = acc[c+3];
    *(float4*)(Zp + c) = v;
  }
}

__global__ __launch_bounds__(256) void d_epi1(const float* __restrict__ Z1,
    const float* __restrict__ Y1s, const float* __restrict__ dis,
    const float* __restrict__ b1, const float* __restrict__ W2,
    float* __restrict__ Y2s)
{
  __shared__ float W2l[DD * CC];
  __shared__ float hl[4][DD];
  const int tid = threadIdx.x;
  *(float4*)(W2l + tid * 4) = *(const float4*)(W2 + tid * 4);
  const int w = tid >> 6, lane = tid & 63;
  const int row = blockIdx.x * 4 + w;
  const size_t o = (size_t)row * DD + lane;
  float z = Y1s[o];
#pragma unroll
  for (int p = 0; p < FKS1; ++p) z += Z1[(size_t)p * BN * DD + o];
  const float dv = dis[row];
  float h = fmaxf(dv * z + b1[lane], 0.f);
  const unsigned bits = tf_bits((unsigned)o);
  h = (bits >> 31) ? 0.f : (h + h);
  hl[w][lane] = h;
  __syncthreads();
  const int wr = tid >> 6, l = tid & 63;
  const int c = l & 15, kq = l >> 4;
  float p = 0.f;
#pragma unroll
  for (int kk = 0; kk < 16; ++kk)
    p += hl[wr][kq * 16 + kk] * W2l[(kq * 16 + kk) * CC + c];
  p += __shfl_xor(p, 16, 64);
  p += __shfl_xor(p, 32, 64);
  if (l < 16) {
    const int rg = blockIdx.x * 4 + wr;
    Y2s[(size_t)rg * CC + c] = dis[rg] * p;
  }
}

__global__ __launch_bounds__(256) void d_gemm2(const float* __restrict__ A,
    const float* __restrict__ Y2s, float* __restrict__ Z2)
{
  const int rb = blockIdx.x >> 4, ks = blockIdx.x & (FKS2 - 1);
  const int row = rb * 256 + threadIdx.x;
  const int batch = rb >> 3;
  const int KSEG = NN / FKS2;
  const float* Arow = A + (size_t)row * NN + ks * KSEG;
  const float* Yb = Y2s + (size_t)batch * NN * CC;
  const int kbase = ks * KSEG;
  float acc[16];
#pragma unroll
  for (int c = 0; c < 16; ++c) acc[c] = 0.f;
  float4 a0 = *(const float4*)(Arow);
  float4 a1 = *(const float4*)(Arow + 4);
  for (int k = 0; k < KSEG; k += 8) {
    const int kn = (k + 8 < KSEG) ? (k + 8) : 0;
    float4 n0 = *(const float4*)(Arow + kn);
    float4 n1 = *(const float4*)(Arow + kn + 4);
    const float av[8] = {a0.x, a0.y, a0.z, a0.w, a1.x, a1.y, a1.z, a1.w};
#pragma unroll
    for (int j = 0; j < 8; ++j) {
      const float* yr = Yb + (size_t)(kbase + k + j) * CC;
#pragma unroll
      for (int c = 0; c < 16; ++c) acc[c] += av[j] * yr[c];
    }
    a0 = n0; a1 = n1;
  }
  float* Zp = Z2 + ((size_t)ks * BN + row) * CC;
#pragma unroll
  for (int c = 0; c < 16; c += 4) {
    float4 v; v.x = acc[c]; v.y = acc[c+1]; v.z = acc[c+2]; v.w = acc[c+3];
    *(float4*)(Zp + c) = v;
  }
}

__global__ __launch_bounds__(256) void d_final(const float* __restrict__ Z2,
    const float* __restrict__ Y2s, const float* __restrict__ dis,
    const float* __restrict__ b2, float* __restrict__ out)
{
  const int gid = blockIdx.x * 256 + threadIdx.x;
  const int r = gid >> 2, q = gid & 3;
  const size_t o = (size_t)r * CC + q * 4;
  float4 s = *(const float4*)(Y2s + o);
#pragma unroll
  for (int p = 0; p < FKS2; ++p) {
    const float4 zp = *(const float4*)(Z2 + (size_t)p * BN * CC + o);
    s.x += zp.x; s.y += zp.y; s.z += zp.z; s.w += zp.w;
  }
  const float dv = dis[r];
  const float4 bb = *(const float4*)(b2 + q * 4);
  float4 res;
  res.x = dv * s.x + bb.x;
  res.y = dv * s.y + bb.y;
  res.z = dv * s.z + bb.z;
  res.w = dv * s.w + bb.w;
  *(float4*)(out + o) = res;
}

extern "C" void kernel_launch(void* const* d_in, const int* in_sizes, int n_in,
                              void* d_out, int out_size, void* d_ws, size_t ws_size,
                              hipStream_t stream) {
  const float* X  = (const float*)d_in[0];
  const float* A  = (const float*)d_in[1];
  const float* W1 = (const float*)d_in[2];
  const float* b1 = (const float*)d_in[3];
  const float* W2 = (const float*)d_in[4];
  const float* b2 = (const float*)d_in[5];
  float* out = (float*)d_out;
  char* wsb = (char*)d_ws;

  // ws layout (bytes): Abf 64MB | Y1s 2MB | Y1sT 2MB | Y2sT 0.5MB |
  // S2d 1MB | dis 64KB  => 72,941,568 total
  const size_t NEED = 72941568;
  if (ws_size >= NEED) {
    unsigned short* Abf  = (unsigned short*)wsb;
    unsigned short* Y1s  = (unsigned short*)(wsb + 67108864);
    unsigned short* Y1sT = (unsigned short*)(wsb + 69206016);
    unsigned short* Y2sT = (unsigned short*)(wsb + 71303168);
    float*          S2d  = (float*)(wsb + 71827456);
    float*          dis  = (float*)(wsb + 72876032);

    k_deg   <<<BN / 4,  256, 0, stream>>>(A, X, W1, dis, Abf, Y1s);
    k_tr    <<<BN / 64, 256, 0, stream>>>(Y1s, Y1sT);
    k_gemm1f<<<BN / 16, 256, 0, stream>>>(Abf, Y1sT, Y1s, dis, b1, W2, Y2sT, S2d);
    k_gemm2o<<<1024,    256, 0, stream>>>(Abf, Y2sT, S2d, dis, b2, out);
  } else {
    // fallback: proven fp32 path (R3)
    float* ws  = (float*)d_ws;
    float* dis = ws;
    float* Y1s = ws + 16384;
    float* Z1  = Y1s + (size_t)BN * DD;
    float* Z2  = Z1;
    float* Y2s = Z1 + (size_t)FKS1 * BN * DD;

    d_deg_xw<<<BN / 4,     256, 0, stream>>>(A, X, W1, dis, Y1s);
    d_gemm1 <<<256 * FKS1, 256, 0, stream>>>(A, Y1s, Z1);
    d_epi1  <<<BN / 4,     256, 0, stream>>>(Z1, Y1s, dis, b1, W2, Y2s);
    d_gemm2 <<<64 * FKS2,  256, 0, stream>>>(A, Y2s, Z2);
    d_final <<<256,        256, 0, stream>>>(Z2, Y2s, dis, b2, out);
  }
}